// Round 4
// baseline (89.866 us; speedup 1.0000x reference)
//
#include <hip/hip_runtime.h>
#include <hip/hip_fp16.h>
#include <math.h>

// u_dot_v + sigmoid, D=64.
// R4 = R3 with the compile fix: __builtin_nontemporal_load needs a native
// clang vector type, not HIP's struct float4. Strategy unchanged:
// fp16 table in d_ws (row = 128B = 1 cache line), 8 lanes/edge, non-temporal
// hints on once-touched streams (conversion input, index loads, out store) to
// keep the hot 6.4 MB table resident in each XCD's 4 MiB L2.

#define DOT_D 64

typedef __attribute__((ext_vector_type(4))) float fvec4;

__global__ __launch_bounds__(256) void f32_to_f16_kernel(
    const float* __restrict__ h, __half2* __restrict__ hh, int n4)
{
    int i = blockIdx.x * blockDim.x + threadIdx.x;
    if (i >= n4) return;
    fvec4 v = __builtin_nontemporal_load(((const fvec4*)h) + i);
    hh[2 * i]     = __floats2half2_rn(v.x, v.y);
    hh[2 * i + 1] = __floats2half2_rn(v.z, v.w);
}

__global__ __launch_bounds__(256) void dot_sigmoid_f16_kernel(
    const __half* __restrict__ h,
    const int* __restrict__ src,
    const int* __restrict__ dst,
    float* __restrict__ out,
    int E)
{
    int tid  = blockIdx.x * blockDim.x + threadIdx.x;
    int lane = tid & 7;    // 8 lanes per edge
    int e    = tid >> 3;
    if (e >= E) return;

    int s = __builtin_nontemporal_load(src + e);
    int d = __builtin_nontemporal_load(dst + e);

    // 16 B per lane: 8 halves. Row = 128 B = one cache line (keep cached).
    fvec4 ur = ((const fvec4*)(h + (size_t)s * DOT_D))[lane];
    fvec4 vr = ((const fvec4*)(h + (size_t)d * DOT_D))[lane];
    const __half2* up = (const __half2*)&ur;
    const __half2* vp = (const __half2*)&vr;

    float p = 0.0f;
#pragma unroll
    for (int k = 0; k < 4; ++k) {
        float2 uf = __half22float2(up[k]);
        float2 vf = __half22float2(vp[k]);
        p += uf.x * vf.x + uf.y * vf.y;
    }

    p += __shfl_xor(p, 4);
    p += __shfl_xor(p, 2);
    p += __shfl_xor(p, 1);

    if (lane == 0) {
        float r = 1.0f / (1.0f + __expf(-p));
        __builtin_nontemporal_store(r, out + e);
    }
}

// f32 fallback (R1 kernel) if d_ws is too small for the fp16 table.
__global__ __launch_bounds__(256) void dot_sigmoid_f32_kernel(
    const float* __restrict__ h,
    const int* __restrict__ src,
    const int* __restrict__ dst,
    float* __restrict__ out,
    int E)
{
    int tid  = blockIdx.x * blockDim.x + threadIdx.x;
    int lane = tid & 15;
    int e    = tid >> 4;
    if (e >= E) return;

    int s = src[e];
    int d = dst[e];
    float4 u = ((const float4*)(h + (size_t)s * DOT_D))[lane];
    float4 v = ((const float4*)(h + (size_t)d * DOT_D))[lane];
    float p = u.x * v.x + u.y * v.y + u.z * v.z + u.w * v.w;
    p += __shfl_xor(p, 8);
    p += __shfl_xor(p, 4);
    p += __shfl_xor(p, 2);
    p += __shfl_xor(p, 1);
    if (lane == 0) out[e] = 1.0f / (1.0f + __expf(-p));
}

extern "C" void kernel_launch(void* const* d_in, const int* in_sizes, int n_in,
                              void* d_out, int out_size, void* d_ws, size_t ws_size,
                              hipStream_t stream) {
    const float* h   = (const float*)d_in[0];
    const int*   src = (const int*)d_in[1];
    const int*   dst = (const int*)d_in[2];
    float*       out = (float*)d_out;

    int ND = in_sizes[0];          // N * 64
    int E  = in_sizes[1];
    size_t f16_bytes = (size_t)ND * sizeof(__half);

    if (ws_size >= f16_bytes) {
        __half* hh = (__half*)d_ws;
        int n4 = ND / 4;
        f32_to_f16_kernel<<<(n4 + 255) / 256, 256, 0, stream>>>(h, (__half2*)hh, n4);

        long long total_threads = (long long)E * 8;
        int grid = (int)((total_threads + 255) / 256);
        dot_sigmoid_f16_kernel<<<grid, 256, 0, stream>>>(hh, src, dst, out, E);
    } else {
        long long total_threads = (long long)E * 16;
        int grid = (int)((total_threads + 255) / 256);
        dot_sigmoid_f32_kernel<<<grid, 256, 0, stream>>>(h, src, dst, out, E);
    }
}